// Round 8
// baseline (272.687 us; speedup 1.0000x reference)
//
#include <hip/hip_runtime.h>
#include <hip/hip_bf16.h>
#include <math.h>

// Problem constants
#define BATCH 4
#define SEQ 2048
#define DMODEL 1024
#define NHEADS 16
#define DHEAD 64
#define MTOK (BATCH * SEQ)          // 8192 tokens
#define SCALE_Q 0.125f              // 1/sqrt(64)
#define NCHAIN (BATCH * NHEADS)     // 64
#define CT 64                       // chunk length (timesteps)
#define NC (SEQ / CT)               // 32 chunks per chain
#define SP 72                       // padded LDS row stride (ushorts); 144B
#define QKVS 3072                   // row stride of fused qkv buffer

typedef unsigned short ushort_t;
typedef __attribute__((ext_vector_type(8))) short bf16x8;    // 8 bf16 in 4 VGPRs
typedef __attribute__((ext_vector_type(4))) float f32x4;
typedef __attribute__((ext_vector_type(16))) float f32x16;   // 32x32 acc

__device__ __forceinline__ float bf2f(unsigned short u) {
    return __uint_as_float(((unsigned)u) << 16);
}
__device__ __forceinline__ unsigned short f2bf(float f) {
    unsigned u = __float_as_uint(f);
    return (unsigned short)((u + 0x7fffu + ((u >> 16) & 1u)) >> 16);  // RNE
}

// ---------------------------------------------------------------------------
// Fused: x row fp32->bf16 convert + gate[m][h] = sigmoid(x@Wg^T + bg)
// One block per token. Conversion: 256 x float4. Gate: 16 lanes per head.
// ---------------------------------------------------------------------------
__global__ __launch_bounds__(256) void cvt_x_gate(const float* __restrict__ x,
                                                  const float* __restrict__ Wg,
                                                  const float* __restrict__ bg,
                                                  ushort_t* __restrict__ xb,
                                                  float* __restrict__ gate) {
    const int m = blockIdx.x;
    const int tid = threadIdx.x;
    const float* xr = x + (size_t)m * DMODEL;

    // convert: thread tid handles float4 #tid of the row
    {
        float4 v = ((const float4*)xr)[tid];
        ushort4 o;
        o.x = f2bf(v.x); o.y = f2bf(v.y); o.z = f2bf(v.z); o.w = f2bf(v.w);
        ((ushort4*)(xb + (size_t)m * DMODEL))[tid] = o;
    }

    // gate
    const int h = tid >> 4;
    const int r = tid & 15;
    const float* wr = Wg + (size_t)h * DMODEL;
    float p = 0.f;
#pragma unroll
    for (int i = 0; i < 16; ++i) {
        const int k = (r << 2) + (i << 6);
        float4 xv = *(const float4*)&xr[k];
        float4 wv = *(const float4*)&wr[k];
        p += xv.x * wv.x + xv.y * wv.y + xv.z * wv.z + xv.w * wv.w;
    }
    p += __shfl_xor(p, 8, 64);
    p += __shfl_xor(p, 4, 64);
    p += __shfl_xor(p, 2, 64);
    p += __shfl_xor(p, 1, 64);
    if (r == 0) {
        float vv = p + bg[h];
        gate[(size_t)m * NHEADS + h] = 1.f / (1.f + __expf(-vv));
    }
}

// ---------------------------------------------------------------------------
// Weight concat + convert: rows [0,1024)=Wq, [1024,2048)=Wk, [2048,3072)=Wv,
// [3072,4096)=Wo.  4096x1024 fp32 -> bf16.
// ---------------------------------------------------------------------------
__global__ __launch_bounds__(256) void cvt_weights(const float* __restrict__ Wq,
                                                   const float* __restrict__ Wk,
                                                   const float* __restrict__ Wv,
                                                   const float* __restrict__ Wo,
                                                   ushort_t* __restrict__ dst) {
    int i = blockIdx.x * 256 + threadIdx.x;           // float4 index, < 1048576
    const int row = i >> 8;
    const int c4 = i & 255;
    const float* src;
    if (row < 1024)      src = Wq + (size_t)row * DMODEL;
    else if (row < 2048) src = Wk + (size_t)(row - 1024) * DMODEL;
    else if (row < 3072) src = Wv + (size_t)(row - 2048) * DMODEL;
    else                 src = Wo + (size_t)(row - 3072) * DMODEL;
    float4 v = ((const float4*)src)[c4];
    ushort4 o;
    o.x = f2bf(v.x); o.y = f2bf(v.y); o.z = f2bf(v.z); o.w = f2bf(v.w);
    ((ushort4*)(dst + (size_t)row * DMODEL))[c4] = o;
}

// ---------------------------------------------------------------------------
// bf16 MFMA GEMM: C[M,N] = ep( A[M,K] @ B[N,K]^T )
// 128x128 tile, BK=32, double-buffered LDS (1 barrier/iter), XOR bank swizzle.
// Compute: v_mfma_f32_32x32x16_bf16 (15% better FLOP/cyc than 16x16x32, m119);
// wave tile 64x64 = 2x2 of 32x32, 2 K-halves -> 8 MFMA + 8 ds_read_b128/iter.
// LDS slot s (16B) at row r holds global k-chunk s ^ ((r>>1)&3); fragment
// reads stay 2-way banked (free) -- verified 0 conflicts in R7.
// mode 0: identity -> fp32 Cf
// mode 3: fused QKV epilogue -> bf16 Cb: cols [0,1024) phi(acc*SCALE_Q),
//         [1024,2048) phi(acc), [2048,3072) identity.
// ---------------------------------------------------------------------------
#define GT 128
#define GBK 32

__global__ __launch_bounds__(256) void gemm_bf16(const ushort_t* __restrict__ A,
                                                 const ushort_t* __restrict__ B,
                                                 float* __restrict__ Cf,
                                                 ushort_t* __restrict__ Cb,
                                                 int M, int N, int K,
                                                 int mode) {
    __shared__ ushort_t As[2][GT * GBK];   // 8 KB each buffer
    __shared__ ushort_t Bs[2][GT * GBK];

    const int tid = threadIdx.x;
    const int w = tid >> 6;
    const int l = tid & 63;
    const int m0 = blockIdx.y * GT;
    const int n0 = blockIdx.x * GT;
    const int wm = (w >> 1) * 64;
    const int wn = (w & 1) * 64;

    // staging: lane l -> LDS (row l>>2, slot l&3) of a 16-row segment;
    // swizzle => lane fetches global chunk (l&3) ^ ((l>>3)&3)
    const int srow = l >> 2;
    const int schunk = ((l & 3) ^ ((l >> 3) & 3)) * 8;   // elements

    const ushort_t* aseg[2];
    const ushort_t* bseg[2];
#pragma unroll
    for (int i = 0; i < 2; ++i) {
        const int s = w * 2 + i;
        aseg[i] = A + (size_t)(m0 + s * 16 + srow) * K + schunk;
        bseg[i] = B + (size_t)(n0 + s * 16 + srow) * K + schunk;
    }

#define STAGE(buf, k0)                                                          \
    do {                                                                        \
        _Pragma("unroll")                                                       \
        for (int i_ = 0; i_ < 2; ++i_) {                                        \
            const int s_ = w * 2 + i_;                                          \
            __builtin_amdgcn_global_load_lds(                                   \
                (const __attribute__((address_space(1))) unsigned int*)(const void*)(aseg[i_] + (k0)), \
                (__attribute__((address_space(3))) unsigned int*)(void*)&As[buf][s_ * 16 * GBK], \
                16, 0, 0);                                                      \
            __builtin_amdgcn_global_load_lds(                                   \
                (const __attribute__((address_space(1))) unsigned int*)(const void*)(bseg[i_] + (k0)), \
                (__attribute__((address_space(3))) unsigned int*)(void*)&Bs[buf][s_ * 16 * GBK], \
                16, 0, 0);                                                      \
        }                                                                       \
    } while (0)

    f32x16 acc[2][2];
#pragma unroll
    for (int i = 0; i < 2; ++i)
#pragma unroll
        for (int j = 0; j < 2; ++j)
#pragma unroll
            for (int r = 0; r < 16; ++r) acc[i][j][r] = 0.f;

    // 32x32x16 fragment mapping: row = lane&31, k-off = (lane>>5)*8
    const int fr32 = l & 31;
    const int khalf = l >> 5;
    const int swm = (fr32 >> 1) & 3;     // swizzle mask (row bits 1-2)

    STAGE(0, 0);

    const int nit = K / GBK;
    for (int it = 0; it < nit; ++it) {
        __syncthreads();                  // buf[it&1] DMA landed; old reads done
        if (it + 1 < nit) STAGE((it + 1) & 1, (it + 1) * GBK);

        const ushort_t* __restrict__ as = As[it & 1];
        const ushort_t* __restrict__ bs = Bs[it & 1];

        bf16x8 af[2][2], bfr[2][2];       // [tile][khalf-of-BK32]
#pragma unroll
        for (int ti = 0; ti < 2; ++ti)
#pragma unroll
            for (int h = 0; h < 2; ++h) {
                const int ss = (h * 2 + khalf) ^ swm;
                af[ti][h] = *(const bf16x8*)&as[(wm + ti * 32 + fr32) * GBK + ss * 8];
                bfr[ti][h] = *(const bf16x8*)&bs[(wn + ti * 32 + fr32) * GBK + ss * 8];
            }
#pragma unroll
        for (int ti = 0; ti < 2; ++ti)
#pragma unroll
            for (int tj = 0; tj < 2; ++tj)
#pragma unroll
                for (int h = 0; h < 2; ++h)
                    acc[ti][tj] = __builtin_amdgcn_mfma_f32_32x32x16_bf16(
                        af[ti][h], bfr[tj][h], acc[ti][tj], 0, 0, 0);
    }
#undef STAGE

    // block-uniform epilogue flags
    float escale = 1.0f;
    bool do_phi = false;
    if (mode == 3) {
        do_phi = (n0 < 2048);
        escale = (n0 < 1024) ? SCALE_Q : 1.0f;
    }

    // C/D 32x32: col = lane&31, row = (reg&3) + 8*(reg>>2) + 4*(lane>>5)
#pragma unroll
    for (int ti = 0; ti < 2; ++ti)
#pragma unroll
        for (int tj = 0; tj < 2; ++tj)
#pragma unroll
            for (int r = 0; r < 16; ++r) {
                const int row = m0 + wm + ti * 32 + (r & 3) + 8 * (r >> 2) + 4 * khalf;
                const int col = n0 + wn + tj * 32 + fr32;
                float val = acc[ti][tj][r];
                if (mode == 0) {
                    Cf[(size_t)row * N + col] = val;
                } else {
                    val *= escale;
                    if (do_phi) val = (val > 0.f) ? (val + 1.f) : __expf(val);  // elu+1
                    Cb[(size_t)row * N + col] = f2bf(val);
                }
            }
}

// ---------------------------------------------------------------------------
// Phase 1: per (chain, chunk) tile, decay-weighted KV outer-product sum
//   Dt[j][i] = sum_tau e^{b63 - b_tau} * v[tau][j] * k[tau][i]   (fp32)
// ---------------------------------------------------------------------------
__global__ __launch_bounds__(256) void p1_kernel(const ushort_t* __restrict__ qkv,
                                                 const float* __restrict__ gate,
                                                 float* __restrict__ Dt,
                                                 float* __restrict__ Bg) {
    const int tile = blockIdx.x;          // 0..2047
    const int chain = tile >> 5;
    const int c = tile & 31;
    const int b = chain >> 4;
    const int h = chain & 15;
    const int tid = threadIdx.x;
    const int w = tid >> 6;
    const int l = tid & 63;

    __shared__ ushort_t Ks[CT * SP];
    __shared__ ushort_t Vs[CT * SP];
    __shared__ float bs[CT];

    {
        const int row = tid >> 2;
        const int seg = (tid & 3) * 16;
        const size_t grow = ((size_t)(b * SEQ + c * CT + row)) * QKVS + h * DHEAD + seg;
        float4 a0 = *(const float4*)&qkv[grow + 1024];      // k
        float4 a1 = *(const float4*)&qkv[grow + 1024 + 8];
        float4 b0 = *(const float4*)&qkv[grow + 2048];      // v
        float4 b1 = *(const float4*)&qkv[grow + 2048 + 8];
        *(float4*)&Ks[row * SP + seg]     = a0;
        *(float4*)&Ks[row * SP + seg + 8] = a1;
        *(float4*)&Vs[row * SP + seg]     = b0;
        *(float4*)&Vs[row * SP + seg + 8] = b1;
    }
    if (tid < 64) {
        float g = gate[((size_t)(b * SEQ + c * CT + tid)) * NHEADS + h];
        float lg = __logf(g);
#pragma unroll
        for (int d = 1; d < 64; d <<= 1) {
            float n = __shfl_up(lg, d, 64);
            if (l >= d) lg += n;
        }
        bs[tid] = lg;
        if (tid == 63) Bg[tile] = lg;
    }
    __syncthreads();

    const float B = bs[63];
    const int fr = l & 15;
    const int fq = (l >> 4) * 8;
    const int jw = w * 16;

    f32x4 accD[4];
#pragma unroll
    for (int nt = 0; nt < 4; ++nt)
#pragma unroll
        for (int r = 0; r < 4; ++r) accD[nt][r] = 0.f;

#pragma unroll
    for (int kc = 0; kc < 2; ++kc) {
        float ef[8];
#pragma unroll
        for (int m = 0; m < 8; ++m) ef[m] = __expf(B - bs[kc * 32 + fq + m]);
        bf16x8 va;
#pragma unroll
        for (int m = 0; m < 8; ++m)
            va[m] = (short)Vs[(kc * 32 + fq + m) * SP + jw + fr];
#pragma unroll
        for (int nt = 0; nt < 4; ++nt) {
            bf16x8 kf;
#pragma unroll
            for (int m = 0; m < 8; ++m)
                kf[m] = (short)f2bf(ef[m] * bf2f(Ks[(kc * 32 + fq + m) * SP + nt * 16 + fr]));
            accD[nt] = __builtin_amdgcn_mfma_f32_16x16x32_bf16(va, kf, accD[nt], 0, 0, 0);
        }
    }

    const int er = (l >> 4) * 4;
    const size_t dbase = (size_t)tile * (DHEAD * DHEAD);
#pragma unroll
    for (int nt = 0; nt < 4; ++nt)
#pragma unroll
        for (int r = 0; r < 4; ++r) {
            const int j = jw + er + r;
            const int i = nt * 16 + fr;
            Dt[dbase + j * DHEAD + i] = accD[nt][r];
        }
}

// ---------------------------------------------------------------------------
// Phase 2: sequential over 32 chunks; St[c] = state BEFORE chunk c (bf16,[j][i])
// ---------------------------------------------------------------------------
__global__ __launch_bounds__(256) void p2_kernel(const float* __restrict__ Dt,
                                                 const float* __restrict__ Bg,
                                                 ushort_t* __restrict__ St) {
    const int chain = blockIdx.x >> 2;
    const int jq = (blockIdx.x & 3) * 16;
    const int tid = threadIdx.x;
    const int jj = jq + (tid >> 4);
    const int ii = (tid & 15) * 4;

    float4 S = make_float4(0.f, 0.f, 0.f, 0.f);
    for (int c = 0; c < NC; ++c) {
        const size_t base = (((size_t)chain * NC + c) * DHEAD + jj) * DHEAD + ii;
        ushort4 o;
        o.x = f2bf(S.x); o.y = f2bf(S.y); o.z = f2bf(S.z); o.w = f2bf(S.w);
        *(ushort4*)&St[base] = o;
        const float eB = __expf(Bg[chain * NC + c]);
        const float4 D = *(const float4*)&Dt[base];
        S.x = eB * S.x + D.x;
        S.y = eB * S.y + D.y;
        S.z = eB * S.z + D.z;
        S.w = eB * S.w + D.w;
    }
}

// ---------------------------------------------------------------------------
// Phase 3: Y = diag(e^{b_t}) (Q@St) + (QK^T ⊙ decay ⊙ mask) @ V   -> yb bf16
// P~ LDS round-trip is wave-private by row band -> no barrier needed
// (compiler inserts lgkmcnt waits for the within-wave RAW dependency).
// ---------------------------------------------------------------------------
__global__ __launch_bounds__(256) void p3_kernel(const ushort_t* __restrict__ qkv,
                                                 const ushort_t* __restrict__ St,
                                                 const float* __restrict__ gate,
                                                 ushort_t* __restrict__ yb) {
    const int tile = blockIdx.x;
    const int chain = tile >> 5;
    const int c = tile & 31;
    const int b = chain >> 4;
    const int h = chain & 15;
    const int tid = threadIdx.x;
    const int w = tid >> 6;
    const int l = tid & 63;

    __shared__ ushort_t Qs[CT * SP];
    __shared__ ushort_t Ks[CT * SP];
    __shared__ ushort_t Vs[CT * SP];
    __shared__ ushort_t Ss[CT * SP];
    __shared__ ushort_t Ps[CT * SP];
    __shared__ float bs[CT];

    {
        const int row = tid >> 2;
        const int seg = (tid & 3) * 16;
        const size_t grow = ((size_t)(b * SEQ + c * CT + row)) * QKVS + h * DHEAD + seg;
        float4 q0 = *(const float4*)&qkv[grow];
        float4 q1 = *(const float4*)&qkv[grow + 8];
        float4 k0 = *(const float4*)&qkv[grow + 1024];
        float4 k1 = *(const float4*)&qkv[grow + 1024 + 8];
        float4 v0 = *(const float4*)&qkv[grow + 2048];
        float4 v1 = *(const float4*)&qkv[grow + 2048 + 8];
        const size_t srow = (((size_t)chain * NC + c) * DHEAD + row) * DHEAD + seg;
        float4 s0 = *(const float4*)&St[srow];
        float4 s1 = *(const float4*)&St[srow + 8];
        *(float4*)&Qs[row * SP + seg]     = q0;
        *(float4*)&Qs[row * SP + seg + 8] = q1;
        *(float4*)&Ks[row * SP + seg]     = k0;
        *(float4*)&Ks[row * SP + seg + 8] = k1;
        *(float4*)&Vs[row * SP + seg]     = v0;
        *(float4*)&Vs[row * SP + seg + 8] = v1;
        *(float4*)&Ss[row * SP + seg]     = s0;
        *(float4*)&Ss[row * SP + seg + 8] = s1;
    }
    if (tid < 64) {
        float g = gate[((size_t)(b * SEQ + c * CT + tid)) * NHEADS + h];
        float lg = __logf(g);
#pragma unroll
        for (int d = 1; d < 64; d <<= 1) {
            float n = __shfl_up(lg, d, 64);
            if (l >= d) lg += n;
        }
        bs[tid] = lg;
    }
    __syncthreads();

    const int fr = l & 15;
    const int fq = (l >> 4) * 8;
    const int tw = w * 16;

    bf16x8 qa[2];
#pragma unroll
    for (int kc = 0; kc < 2; ++kc)
        qa[kc] = *(const bf16x8*)&Qs[(tw + fr) * SP + kc * 32 + fq];

    f32x4 accA[4], accP[4];
#pragma unroll
    for (int nt = 0; nt < 4; ++nt)
#pragma unroll
        for (int r = 0; r < 4; ++r) { accA[nt][r] = 0.f; accP[nt][r] = 0.f; }

#pragma unroll
    for (int kc = 0; kc < 2; ++kc)
#pragma unroll
        for (int nt = 0; nt < 4; ++nt) {
            bf16x8 sb = *(const bf16x8*)&Ss[(nt * 16 + fr) * SP + kc * 32 + fq];
            accA[nt] = __builtin_amdgcn_mfma_f32_16x16x32_bf16(qa[kc], sb, accA[nt], 0, 0, 0);
            bf16x8 kf = *(const bf16x8*)&Ks[(nt * 16 + fr) * SP + kc * 32 + fq];
            accP[nt] = __builtin_amdgcn_mfma_f32_16x16x32_bf16(qa[kc], kf, accP[nt], 0, 0, 0);
        }

    const int er = (l >> 4) * 4;
    int trow[4];
    float bt[4];
#pragma unroll
    for (int r = 0; r < 4; ++r) { trow[r] = tw + er + r; bt[r] = bs[trow[r]]; }
#pragma unroll
    for (int nt = 0; nt < 4; ++nt) {
        const int tau = nt * 16 + fr;
        const float btau = bs[tau];
#pragma unroll
        for (int r = 0; r < 4; ++r) {
            float f = (tau <= trow[r]) ? __expf(bt[r] - btau) : 0.f;
            Ps[trow[r] * SP + tau] = f2bf(accP[nt][r] * f);
        }
    }
    // no barrier: P~ rows are wave-private (write band == read band per wave)

    f32x4 accY[4];
#pragma unroll
    for (int r = 0; r < 4; ++r) {
        const float eb = __expf(bt[r]);
#pragma unroll
        for (int nt = 0; nt < 4; ++nt) accY[nt][r] = accA[nt][r] * eb;
    }
#pragma unroll
    for (int kc = 0; kc < 2; ++kc) {
        bf16x8 pa = *(const bf16x8*)&Ps[(tw + fr) * SP + kc * 32 + fq];
#pragma unroll
        for (int nt = 0; nt < 4; ++nt) {
            bf16x8 vf;
#pragma unroll
            for (int m = 0; m < 8; ++m)
                vf[m] = (short)Vs[(kc * 32 + fq + m) * SP + nt * 16 + fr];
            accY[nt] = __builtin_amdgcn_mfma_f32_16x16x32_bf16(pa, vf, accY[nt], 0, 0, 0);
        }
    }

    const size_t ybase = ((size_t)(b * SEQ + c * CT)) * DMODEL + h * DHEAD;
#pragma unroll
    for (int nt = 0; nt < 4; ++nt)
#pragma unroll
        for (int r = 0; r < 4; ++r)
            yb[ybase + (size_t)trow[r] * DMODEL + nt * 16 + fr] = f2bf(accY[nt][r]);
}

// ---------------------------------------------------------------------------
// Host launch
// ---------------------------------------------------------------------------
extern "C" void kernel_launch(void* const* d_in, const int* in_sizes, int n_in,
                              void* d_out, int out_size, void* d_ws, size_t ws_size,
                              hipStream_t stream) {
    const float* x  = (const float*)d_in[0];
    const float* Wq = (const float*)d_in[1];
    const float* Wk = (const float*)d_in[2];
    const float* Wv = (const float*)d_in[3];
    const float* Wo = (const float*)d_in[4];
    const float* Wg = (const float*)d_in[5];
    const float* bg = (const float*)d_in[6];
    float* out = (float*)d_out;

    const size_t elems = (size_t)MTOK * DMODEL;     // 8,388,608
    const size_t welems = (size_t)DMODEL * DMODEL;  // 1,048,576
    const size_t stelems = (size_t)NCHAIN * NC * DHEAD * DHEAD;   // 8,388,608

    // layout with aliasing:
    // [xb | St (after p2)] [qkv] [wcat 4W] [gate f32] [Bg f32] [Dt f32 | yb (after p2)]
    ushort_t* xb   = (ushort_t*)d_ws;
    ushort_t* St   = xb;                            // alias: xb dead after QKV gemm
    ushort_t* qkv  = xb + elems;                    // [8192][3072]
    ushort_t* wcat = qkv + (size_t)MTOK * QKVS;     // rows: Wq,Wk,Wv,Wo
    float* gate    = (float*)(wcat + 4 * welems);
    float* Bg      = gate + (size_t)MTOK * NHEADS;
    float* Dt      = Bg + (size_t)NCHAIN * NC;
    ushort_t* yb   = (ushort_t*)Dt;                 // alias: Dt dead after p2

    const size_t need = (size_t)((char*)(Dt + stelems) - (char*)d_ws);  // ~105 MB
    if (ws_size < need) return;

    // converts + gate (2 launches)
    cvt_x_gate<<<dim3(MTOK), dim3(256), 0, stream>>>(x, Wg, bg, xb, gate);
    cvt_weights<<<dim3((int)(4 * welems / 4 / 256)), dim3(256), 0, stream>>>(Wq, Wk, Wv, Wo, wcat);

    // fused QKV projection: N=3072, epilogue per column range
    gemm_bf16<<<dim3(QKVS / GT, MTOK / GT), dim3(256), 0, stream>>>(
        xb, wcat, nullptr, qkv, MTOK, QKVS, DMODEL, 3);

    // chunked linear-attention scan
    p1_kernel<<<dim3(NCHAIN * NC), dim3(256), 0, stream>>>(qkv, gate, Dt, Bg);
    p2_kernel<<<dim3(NCHAIN * 4), dim3(256), 0, stream>>>(Dt, Bg, St);
    p3_kernel<<<dim3(NCHAIN * NC), dim3(256), 0, stream>>>(qkv, St, gate, yb);

    // output projection (fp32 out)
    gemm_bf16<<<dim3(DMODEL / GT, MTOK / GT), dim3(256), 0, stream>>>(
        yb, wcat + 3 * welems, out, nullptr, MTOK, DMODEL, DMODEL, 0);
}

// Round 9
// 267.199 us; speedup vs baseline: 1.0205x; 1.0205x over previous
//
#include <hip/hip_runtime.h>
#include <hip/hip_bf16.h>
#include <math.h>

// Problem constants
#define BATCH 4
#define SEQ 2048
#define DMODEL 1024
#define NHEADS 16
#define DHEAD 64
#define MTOK (BATCH * SEQ)          // 8192 tokens
#define SCALE_Q 0.125f              // 1/sqrt(64)
#define NCHAIN (BATCH * NHEADS)     // 64
#define CT 64                       // chunk length (timesteps)
#define NC (SEQ / CT)               // 32 chunks per chain
#define SP 72                       // padded LDS row stride (ushorts); 144B
#define QKVS 3072                   // row stride of fused qkv buffer

typedef unsigned short ushort_t;
typedef __attribute__((ext_vector_type(8))) short bf16x8;   // 8 bf16 in 4 VGPRs
typedef __attribute__((ext_vector_type(4))) float f32x4;

__device__ __forceinline__ float bf2f(unsigned short u) {
    return __uint_as_float(((unsigned)u) << 16);
}
__device__ __forceinline__ unsigned short f2bf(float f) {
    unsigned u = __float_as_uint(f);
    return (unsigned short)((u + 0x7fffu + ((u >> 16) & 1u)) >> 16);  // RNE
}

// ---------------------------------------------------------------------------
// Merged converts: blocks [0,8192) = x row fp32->bf16 + gate GEMV;
// blocks [8192,12288) = one weight row each (Wq|Wk|Wv|Wo concat -> bf16).
// ---------------------------------------------------------------------------
__global__ __launch_bounds__(256) void cvt_all(const float* __restrict__ x,
                                               const float* __restrict__ Wq,
                                               const float* __restrict__ Wk,
                                               const float* __restrict__ Wv,
                                               const float* __restrict__ Wo,
                                               const float* __restrict__ Wg,
                                               const float* __restrict__ bg,
                                               ushort_t* __restrict__ xb,
                                               ushort_t* __restrict__ wcat,
                                               float* __restrict__ gate) {
    const int blk = blockIdx.x;
    const int tid = threadIdx.x;

    if (blk < MTOK) {
        const int m = blk;
        const float* xr = x + (size_t)m * DMODEL;
        // convert: thread tid handles float4 #tid of the row
        {
            float4 v = ((const float4*)xr)[tid];
            ushort4 o;
            o.x = f2bf(v.x); o.y = f2bf(v.y); o.z = f2bf(v.z); o.w = f2bf(v.w);
            ((ushort4*)(xb + (size_t)m * DMODEL))[tid] = o;
        }
        // gate: 16 lanes per head
        const int h = tid >> 4;
        const int r = tid & 15;
        const float* wr = Wg + (size_t)h * DMODEL;
        float p = 0.f;
#pragma unroll
        for (int i = 0; i < 16; ++i) {
            const int k = (r << 2) + (i << 6);
            float4 xv = *(const float4*)&xr[k];
            float4 wv = *(const float4*)&wr[k];
            p += xv.x * wv.x + xv.y * wv.y + xv.z * wv.z + xv.w * wv.w;
        }
        p += __shfl_xor(p, 8, 64);
        p += __shfl_xor(p, 4, 64);
        p += __shfl_xor(p, 2, 64);
        p += __shfl_xor(p, 1, 64);
        if (r == 0) {
            float vv = p + bg[h];
            gate[(size_t)m * NHEADS + h] = 1.f / (1.f + __expf(-vv));
        }
    } else {
        const int row = blk - MTOK;                  // 0..4095
        const float* src;
        if (row < 1024)      src = Wq + (size_t)row * DMODEL;
        else if (row < 2048) src = Wk + (size_t)(row - 1024) * DMODEL;
        else if (row < 3072) src = Wv + (size_t)(row - 2048) * DMODEL;
        else                 src = Wo + (size_t)(row - 3072) * DMODEL;
        float4 v = ((const float4*)src)[tid];
        ushort4 o;
        o.x = f2bf(v.x); o.y = f2bf(v.y); o.z = f2bf(v.z); o.w = f2bf(v.w);
        ((ushort4*)(wcat + (size_t)row * DMODEL))[tid] = o;
    }
}

// ---------------------------------------------------------------------------
// bf16 MFMA GEMM: C[M,N] = ep( A[M,K] @ B[N,K]^T )     [R7 verified config]
// 128x128 tile, BK=32, double-buffered LDS (1 barrier/iter), XOR bank swizzle.
// 16x16x32 MFMA; fragment ds_read_b128 2-way banked (free) — 0 conflicts (R7).
// mode 0: identity -> fp32 Cf
// mode 3: fused QKV epilogue -> bf16 Cb: cols [0,1024) phi(acc*SCALE_Q),
//         [1024,2048) phi(acc), [2048,3072) identity.
// ---------------------------------------------------------------------------
#define GT 128
#define GBK 32

__global__ __launch_bounds__(256) void gemm_bf16(const ushort_t* __restrict__ A,
                                                 const ushort_t* __restrict__ B,
                                                 float* __restrict__ Cf,
                                                 ushort_t* __restrict__ Cb,
                                                 int M, int N, int K,
                                                 int mode) {
    __shared__ ushort_t As[2][GT * GBK];   // 8 KB each buffer
    __shared__ ushort_t Bs[2][GT * GBK];

    const int tid = threadIdx.x;
    const int w = tid >> 6;
    const int l = tid & 63;
    const int m0 = blockIdx.y * GT;
    const int n0 = blockIdx.x * GT;
    const int wm = (w >> 1) * 64;
    const int wn = (w & 1) * 64;

    // staging: lane l -> LDS (row l>>2, slot l&3) of a 16-row segment;
    // swizzle => lane fetches global chunk (l&3) ^ ((l>>3)&3)
    const int srow = l >> 2;
    const int schunk = ((l & 3) ^ ((l >> 3) & 3)) * 8;   // elements

    const ushort_t* aseg[2];
    const ushort_t* bseg[2];
#pragma unroll
    for (int i = 0; i < 2; ++i) {
        const int s = w * 2 + i;
        aseg[i] = A + (size_t)(m0 + s * 16 + srow) * K + schunk;
        bseg[i] = B + (size_t)(n0 + s * 16 + srow) * K + schunk;
    }

#define STAGE(buf, k0)                                                          \
    do {                                                                        \
        _Pragma("unroll")                                                       \
        for (int i_ = 0; i_ < 2; ++i_) {                                        \
            const int s_ = w * 2 + i_;                                          \
            __builtin_amdgcn_global_load_lds(                                   \
                (const __attribute__((address_space(1))) unsigned int*)(const void*)(aseg[i_] + (k0)), \
                (__attribute__((address_space(3))) unsigned int*)(void*)&As[buf][s_ * 16 * GBK], \
                16, 0, 0);                                                      \
            __builtin_amdgcn_global_load_lds(                                   \
                (const __attribute__((address_space(1))) unsigned int*)(const void*)(bseg[i_] + (k0)), \
                (__attribute__((address_space(3))) unsigned int*)(void*)&Bs[buf][s_ * 16 * GBK], \
                16, 0, 0);                                                      \
        }                                                                       \
    } while (0)

    f32x4 acc[4][4];
#pragma unroll
    for (int i = 0; i < 4; ++i)
#pragma unroll
        for (int j = 0; j < 4; ++j)
#pragma unroll
            for (int r = 0; r < 4; ++r) acc[i][j][r] = 0.f;

    const int fr = l & 15;
    // swizzled fragment slot: logical chunk c = l>>4 at row ...+fr
    const int fsw = (((l >> 4) ^ ((fr >> 1) & 3))) * 8;   // elements

    STAGE(0, 0);

    const int nit = K / GBK;
    for (int it = 0; it < nit; ++it) {
        __syncthreads();                  // buf[it&1] DMA landed; old reads done
        if (it + 1 < nit) STAGE((it + 1) & 1, (it + 1) * GBK);

        const ushort_t* __restrict__ as = As[it & 1];
        const ushort_t* __restrict__ bs = Bs[it & 1];

        bf16x8 af[4], bfr[4];
#pragma unroll
        for (int ti = 0; ti < 4; ++ti)
            af[ti] = *(const bf16x8*)&as[(wm + ti * 16 + fr) * GBK + fsw];
#pragma unroll
        for (int tj = 0; tj < 4; ++tj)
            bfr[tj] = *(const bf16x8*)&bs[(wn + tj * 16 + fr) * GBK + fsw];
#pragma unroll
        for (int ti = 0; ti < 4; ++ti)
#pragma unroll
            for (int tj = 0; tj < 4; ++tj)
                acc[ti][tj] = __builtin_amdgcn_mfma_f32_16x16x32_bf16(
                    af[ti], bfr[tj], acc[ti][tj], 0, 0, 0);
    }
#undef STAGE

    // block-uniform epilogue flags
    float escale = 1.0f;
    bool do_phi = false;
    if (mode == 3) {
        do_phi = (n0 < 2048);
        escale = (n0 < 1024) ? SCALE_Q : 1.0f;
    }

    const int er = (l >> 4) * 4;
    const int ec = l & 15;
#pragma unroll
    for (int ti = 0; ti < 4; ++ti)
#pragma unroll
        for (int tj = 0; tj < 4; ++tj)
#pragma unroll
            for (int r = 0; r < 4; ++r) {
                const int row = m0 + wm + ti * 16 + er + r;
                const int col = n0 + wn + tj * 16 + ec;
                float val = acc[ti][tj][r];
                if (mode == 0) {
                    Cf[(size_t)row * N + col] = val;
                } else {
                    val *= escale;
                    if (do_phi) val = (val > 0.f) ? (val + 1.f) : __expf(val);  // elu+1
                    Cb[(size_t)row * N + col] = f2bf(val);
                }
            }
}

// ---------------------------------------------------------------------------
// Phase 1: per (chain, chunk) tile, decay-weighted KV outer-product sum
//   Dt[j][i] = sum_tau e^{b63 - b_tau} * v[tau][j] * k[tau][i]   (fp32)
// K',V staged FEATURE-MAJOR (transposed, decay fused into K-scatter) so all
// MFMA fragment reads are contiguous ds_read_b128 (72-stride, conflict-free).
// ---------------------------------------------------------------------------
__global__ __launch_bounds__(256) void p1_kernel(const ushort_t* __restrict__ qkv,
                                                 const float* __restrict__ gate,
                                                 float* __restrict__ Dt,
                                                 float* __restrict__ Bg) {
    const int tile = blockIdx.x;          // 0..2047
    const int chain = tile >> 5;
    const int c = tile & 31;
    const int b = chain >> 4;
    const int h = chain & 15;
    const int tid = threadIdx.x;
    const int w = tid >> 6;
    const int l = tid & 63;

    __shared__ ushort_t Kt[DHEAD * SP];   // Kt[i][tau], decayed
    __shared__ ushort_t Vt[DHEAD * SP];   // Vt[j][tau]
    __shared__ float bs[CT];

    // global read: thread -> timestep tau = tid>>2, features seg..seg+15
    const int tau = tid >> 2;
    const int seg = (tid & 3) * 16;
    const size_t grow = ((size_t)(b * SEQ + c * CT + tau)) * QKVS + h * DHEAD + seg;
    union { float4 f4[2]; ushort_t us[16]; } uk, uv;
    uk.f4[0] = *(const float4*)&qkv[grow + 1024];
    uk.f4[1] = *(const float4*)&qkv[grow + 1024 + 8];
    uv.f4[0] = *(const float4*)&qkv[grow + 2048];
    uv.f4[1] = *(const float4*)&qkv[grow + 2048 + 8];

    // cumulative log-gate scan (wave 0)
    if (tid < 64) {
        float g = gate[((size_t)(b * SEQ + c * CT + tid)) * NHEADS + h];
        float lg = __logf(g);
#pragma unroll
        for (int d = 1; d < 64; d <<= 1) {
            float n = __shfl_up(lg, d, 64);
            if (l >= d) lg += n;
        }
        bs[tid] = lg;
        if (tid == 63) Bg[tile] = lg;
    }
    __syncthreads();

    // transposed scatter with fused decay on K
    const float e = __expf(bs[63] - bs[tau]);
#pragma unroll
    for (int f = 0; f < 16; ++f) {
        Kt[(seg + f) * SP + tau] = f2bf(e * bf2f(uk.us[f]));
        Vt[(seg + f) * SP + tau] = uv.us[f];
    }
    __syncthreads();

    const int fr = l & 15;
    const int fq = (l >> 4) * 8;
    const int jw = w * 16;

    f32x4 accD[4];
#pragma unroll
    for (int nt = 0; nt < 4; ++nt)
#pragma unroll
        for (int r = 0; r < 4; ++r) accD[nt][r] = 0.f;

#pragma unroll
    for (int kc = 0; kc < 2; ++kc) {
        bf16x8 va = *(const bf16x8*)&Vt[(jw + fr) * SP + kc * 32 + fq];
#pragma unroll
        for (int nt = 0; nt < 4; ++nt) {
            bf16x8 kf = *(const bf16x8*)&Kt[(nt * 16 + fr) * SP + kc * 32 + fq];
            accD[nt] = __builtin_amdgcn_mfma_f32_16x16x32_bf16(va, kf, accD[nt], 0, 0, 0);
        }
    }

    const int er = (l >> 4) * 4;
    const size_t dbase = (size_t)tile * (DHEAD * DHEAD);
#pragma unroll
    for (int nt = 0; nt < 4; ++nt)
#pragma unroll
        for (int r = 0; r < 4; ++r) {
            const int j = jw + er + r;
            const int i = nt * 16 + fr;
            Dt[dbase + j * DHEAD + i] = accD[nt][r];
        }
}

// ---------------------------------------------------------------------------
// Phase 2: sequential over 32 chunks; St[c] = state BEFORE chunk c (bf16,[j][i])
// ---------------------------------------------------------------------------
__global__ __launch_bounds__(256) void p2_kernel(const float* __restrict__ Dt,
                                                 const float* __restrict__ Bg,
                                                 ushort_t* __restrict__ St) {
    const int chain = blockIdx.x >> 2;
    const int jq = (blockIdx.x & 3) * 16;
    const int tid = threadIdx.x;
    const int jj = jq + (tid >> 4);
    const int ii = (tid & 15) * 4;

    float4 S = make_float4(0.f, 0.f, 0.f, 0.f);
    for (int c = 0; c < NC; ++c) {
        const size_t base = (((size_t)chain * NC + c) * DHEAD + jj) * DHEAD + ii;
        ushort4 o;
        o.x = f2bf(S.x); o.y = f2bf(S.y); o.z = f2bf(S.z); o.w = f2bf(S.w);
        *(ushort4*)&St[base] = o;
        const float eB = __expf(Bg[chain * NC + c]);
        const float4 D = *(const float4*)&Dt[base];
        S.x = eB * S.x + D.x;
        S.y = eB * S.y + D.y;
        S.z = eB * S.z + D.z;
        S.w = eB * S.w + D.w;
    }
}

// ---------------------------------------------------------------------------
// Phase 3: Y = diag(e^{b_t}) (Q@St) + (QK^T ⊙ decay ⊙ mask) @ V   -> yb bf16
// Q,K,St time-major; V staged FEATURE-MAJOR (Vt[j][tau]) so the PV B-operand
// is a contiguous ds_read_b128. P~ LDS round-trip is wave-private (no barrier).
// ---------------------------------------------------------------------------
__global__ __launch_bounds__(256) void p3_kernel(const ushort_t* __restrict__ qkv,
                                                 const ushort_t* __restrict__ St,
                                                 const float* __restrict__ gate,
                                                 ushort_t* __restrict__ yb) {
    const int tile = blockIdx.x;
    const int chain = tile >> 5;
    const int c = tile & 31;
    const int b = chain >> 4;
    const int h = chain & 15;
    const int tid = threadIdx.x;
    const int w = tid >> 6;
    const int l = tid & 63;

    __shared__ ushort_t Qs[CT * SP];
    __shared__ ushort_t Ks[CT * SP];
    __shared__ ushort_t Vt[DHEAD * SP];   // feature-major
    __shared__ ushort_t Ss[CT * SP];
    __shared__ ushort_t Ps[CT * SP];
    __shared__ float bs[CT];

    {
        const int row = tid >> 2;              // timestep tau
        const int seg = (tid & 3) * 16;
        const size_t grow = ((size_t)(b * SEQ + c * CT + row)) * QKVS + h * DHEAD + seg;
        float4 q0 = *(const float4*)&qkv[grow];
        float4 q1 = *(const float4*)&qkv[grow + 8];
        float4 k0 = *(const float4*)&qkv[grow + 1024];
        float4 k1 = *(const float4*)&qkv[grow + 1024 + 8];
        union { float4 f4[2]; ushort_t us[16]; } uv;
        uv.f4[0] = *(const float4*)&qkv[grow + 2048];
        uv.f4[1] = *(const float4*)&qkv[grow + 2048 + 8];
        const size_t srow = (((size_t)chain * NC + c) * DHEAD + row) * DHEAD + seg;
        float4 s0 = *(const float4*)&St[srow];
        float4 s1 = *(const float4*)&St[srow + 8];
        *(float4*)&Qs[row * SP + seg]     = q0;
        *(float4*)&Qs[row * SP + seg + 8] = q1;
        *(float4*)&Ks[row * SP + seg]     = k0;
        *(float4*)&Ks[row * SP + seg + 8] = k1;
        *(float4*)&Ss[row * SP + seg]     = s0;
        *(float4*)&Ss[row * SP + seg + 8] = s1;
#pragma unroll
        for (int f = 0; f < 16; ++f)
            Vt[(seg + f) * SP + row] = uv.us[f];
    }
    if (tid < 64) {
        float g = gate[((size_t)(b * SEQ + c * CT + tid)) * NHEADS + h];
        float lg = __logf(g);
#pragma unroll
        for (int d = 1; d < 64; d <<= 1) {
            float n = __shfl_up(lg, d, 64);
            if (l >= d) lg += n;
        }
        bs[tid] = lg;
    }
    __syncthreads();

    const int fr = l & 15;
    const int fq = (l >> 4) * 8;
    const int tw = w * 16;

    bf16x8 qa[2];
#pragma unroll
    for (int kc = 0; kc < 2; ++kc)
        qa[kc] = *(const bf16x8*)&Qs[(tw + fr) * SP + kc * 32 + fq];

    f32x4 accA[4], accP[4];
#pragma unroll
    for (int nt = 0; nt < 4; ++nt)
#pragma unroll
        for (int r = 0; r < 4; ++r) { accA[nt][r] = 0.f; accP[nt][r] = 0.f; }

#pragma unroll
    for (int kc = 0; kc < 2; ++kc)
#pragma unroll
        for (int nt = 0; nt < 4; ++nt) {
            bf16x8 sb = *(const bf16x8*)&Ss[(nt * 16 + fr) * SP + kc * 32 + fq];
            accA[nt] = __builtin_amdgcn_mfma_f32_16x16x32_bf16(qa[kc], sb, accA[nt], 0, 0, 0);
            bf16x8 kf = *(const bf16x8*)&Ks[(nt * 16 + fr) * SP + kc * 32 + fq];
            accP[nt] = __builtin_amdgcn_mfma_f32_16x16x32_bf16(qa[kc], kf, accP[nt], 0, 0, 0);
        }

    const int er = (l >> 4) * 4;
    int trow[4];
    float bt[4];
#pragma unroll
    for (int r = 0; r < 4; ++r) { trow[r] = tw + er + r; bt[r] = bs[trow[r]]; }
#pragma unroll
    for (int nt = 0; nt < 4; ++nt) {
        const int tau = nt * 16 + fr;
        const float btau = bs[tau];
#pragma unroll
        for (int r = 0; r < 4; ++r) {
            float f = (tau <= trow[r]) ? __expf(bt[r] - btau) : 0.f;
            Ps[trow[r] * SP + tau] = f2bf(accP[nt][r] * f);
        }
    }
    // no barrier: P~ rows are wave-private (write band == read band per wave)

    f32x4 accY[4];
#pragma unroll
    for (int r = 0; r < 4; ++r) {
        const float eb = __expf(bt[r]);
#pragma unroll
        for (int nt = 0; nt < 4; ++nt) accY[nt][r] = accA[nt][r] * eb;
    }
#pragma unroll
    for (int kc = 0; kc < 2; ++kc) {
        bf16x8 pa = *(const bf16x8*)&Ps[(tw + fr) * SP + kc * 32 + fq];
#pragma unroll
        for (int nt = 0; nt < 4; ++nt) {
            bf16x8 vf = *(const bf16x8*)&Vt[(nt * 16 + fr) * SP + kc * 32 + fq];
            accY[nt] = __builtin_amdgcn_mfma_f32_16x16x32_bf16(pa, vf, accY[nt], 0, 0, 0);
        }
    }

    const size_t ybase = ((size_t)(b * SEQ + c * CT)) * DMODEL + h * DHEAD;
#pragma unroll
    for (int nt = 0; nt < 4; ++nt)
#pragma unroll
        for (int r = 0; r < 4; ++r)
            yb[ybase + (size_t)trow[r] * DMODEL + nt * 16 + fr] = f2bf(accY[nt][r]);
}

// ---------------------------------------------------------------------------
// Host launch
// ---------------------------------------------------------------------------
extern "C" void kernel_launch(void* const* d_in, const int* in_sizes, int n_in,
                              void* d_out, int out_size, void* d_ws, size_t ws_size,
                              hipStream_t stream) {
    const float* x  = (const float*)d_in[0];
    const float* Wq = (const float*)d_in[1];
    const float* Wk = (const float*)d_in[2];
    const float* Wv = (const float*)d_in[3];
    const float* Wo = (const float*)d_in[4];
    const float* Wg = (const float*)d_in[5];
    const float* bg = (const float*)d_in[6];
    float* out = (float*)d_out;

    const size_t elems = (size_t)MTOK * DMODEL;     // 8,388,608
    const size_t welems = (size_t)DMODEL * DMODEL;  // 1,048,576
    const size_t stelems = (size_t)NCHAIN * NC * DHEAD * DHEAD;   // 8,388,608

    // layout with aliasing:
    // [xb | St (after p2)] [qkv] [wcat 4W] [gate f32] [Bg f32] [Dt f32 | yb (after p2)]
    ushort_t* xb   = (ushort_t*)d_ws;
    ushort_t* St   = xb;                            // alias: xb dead after QKV gemm
    ushort_t* qkv  = xb + elems;                    // [8192][3072]
    ushort_t* wcat = qkv + (size_t)MTOK * QKVS;     // rows: Wq,Wk,Wv,Wo
    float* gate    = (float*)(wcat + 4 * welems);
    float* Bg      = gate + (size_t)MTOK * NHEADS;
    float* Dt      = Bg + (size_t)NCHAIN * NC;
    ushort_t* yb   = (ushort_t*)Dt;                 // alias: Dt dead after p2

    const size_t need = (size_t)((char*)(Dt + stelems) - (char*)d_ws);  // ~105 MB
    if (ws_size < need) return;

    // converts + gate (1 launch)
    cvt_all<<<dim3(MTOK + 4096), dim3(256), 0, stream>>>(x, Wq, Wk, Wv, Wo, Wg, bg,
                                                         xb, wcat, gate);

    // fused QKV projection: N=3072, epilogue per column range
    gemm_bf16<<<dim3(QKVS / GT, MTOK / GT), dim3(256), 0, stream>>>(
        xb, wcat, nullptr, qkv, MTOK, QKVS, DMODEL, 3);

    // chunked linear-attention scan
    p1_kernel<<<dim3(NCHAIN * NC), dim3(256), 0, stream>>>(qkv, gate, Dt, Bg);
    p2_kernel<<<dim3(NCHAIN * 4), dim3(256), 0, stream>>>(Dt, Bg, St);
    p3_kernel<<<dim3(NCHAIN * NC), dim3(256), 0, stream>>>(qkv, St, gate, yb);

    // output projection (fp32 out)
    gemm_bf16<<<dim3(DMODEL / GT, MTOK / GT), dim3(256), 0, stream>>>(
        yb, wcat + 3 * welems, out, nullptr, MTOK, DMODEL, DMODEL, 0);
}

// Round 10
// 243.194 us; speedup vs baseline: 1.1213x; 1.0987x over previous
//
#include <hip/hip_runtime.h>
#include <hip/hip_bf16.h>
#include <math.h>

// Problem constants
#define BATCH 4
#define SEQ 2048
#define DMODEL 1024
#define NHEADS 16
#define DHEAD 64
#define MTOK (BATCH * SEQ)          // 8192 tokens
#define SCALE_Q 0.125f              // 1/sqrt(64)
#define NCHAIN (BATCH * NHEADS)     // 64
#define CT 64                       // chunk length (timesteps)
#define NC (SEQ / CT)               // 32 chunks per chain
#define SP 72                       // padded LDS row stride (ushorts); 144B
#define QKVS 3072                   // row stride of fused qkv buffer
#define WROWS 4224                  // wcat rows: 3072 qkv | 16 Wg | 112 zero | 1024 Wo

typedef unsigned short ushort_t;
typedef __attribute__((ext_vector_type(8))) short bf16x8;   // 8 bf16 in 4 VGPRs
typedef __attribute__((ext_vector_type(4))) float f32x4;

__device__ __forceinline__ float bf2f(unsigned short u) {
    return __uint_as_float(((unsigned)u) << 16);
}
__device__ __forceinline__ unsigned short f2bf(float f) {
    unsigned u = __float_as_uint(f);
    return (unsigned short)((u + 0x7fffu + ((u >> 16) & 1u)) >> 16);  // RNE
}

// ---------------------------------------------------------------------------
// Converts (pure bandwidth now — gate GEMV moved into the QKV GEMM):
// blocks [0,8192): x row fp32->bf16.
// blocks [8192,8192+4224): wcat row r: [0,3072)=Wq|Wk|Wv, [3072,3088)=Wg,
//   [3088,3200)=zeros (MFMA pad), [3200,4224)=Wo.
// ---------------------------------------------------------------------------
__global__ __launch_bounds__(256) void cvt_all(const float* __restrict__ x,
                                               const float* __restrict__ Wq,
                                               const float* __restrict__ Wk,
                                               const float* __restrict__ Wv,
                                               const float* __restrict__ Wo,
                                               const float* __restrict__ Wg,
                                               ushort_t* __restrict__ xb,
                                               ushort_t* __restrict__ wcat) {
    const int blk = blockIdx.x;
    const int tid = threadIdx.x;

    if (blk < MTOK) {
        const float* xr = x + (size_t)blk * DMODEL;
        float4 v = ((const float4*)xr)[tid];
        ushort4 o;
        o.x = f2bf(v.x); o.y = f2bf(v.y); o.z = f2bf(v.z); o.w = f2bf(v.w);
        ((ushort4*)(xb + (size_t)blk * DMODEL))[tid] = o;
    } else {
        const int row = blk - MTOK;                  // 0..4223
        ushort4 o;
        if (row >= 3088 && row < 3200) {
            o.x = o.y = o.z = o.w = 0;
        } else {
            const float* src;
            if (row < 1024)      src = Wq + (size_t)row * DMODEL;
            else if (row < 2048) src = Wk + (size_t)(row - 1024) * DMODEL;
            else if (row < 3072) src = Wv + (size_t)(row - 2048) * DMODEL;
            else if (row < 3088) src = Wg + (size_t)(row - 3072) * DMODEL;
            else                 src = Wo + (size_t)(row - 3200) * DMODEL;
            float4 v = ((const float4*)src)[tid];
            o.x = f2bf(v.x); o.y = f2bf(v.y); o.z = f2bf(v.z); o.w = f2bf(v.w);
        }
        ((ushort4*)(wcat + (size_t)row * DMODEL))[tid] = o;
    }
}

// ---------------------------------------------------------------------------
// bf16 MFMA GEMM: C = ep( A[M,K] @ B[N,K]^T )      [R7-verified core config]
// 128x128 tile, BK=32, double-buffered LDS (1 barrier/iter), XOR bank swizzle,
// 16x16x32 MFMA (0 LDS conflicts — R7). 1D grid with XCD-aware swizzle:
// XCD k (= blk&7) owns row-tile band [8k,8k+8), traversed column-major, so
// its 2 MB A-band stays L2-resident (barrier drains on L2 hits, not HBM).
// mode 0: identity -> fp32 Cf (stride N)
// mode 3: fused QKV+gate: col tiles 0..7 phi(acc*SCALE_Q), 8..15 phi(acc),
//         16..23 identity -> bf16 Cb (stride QKVS); col tile 24 = gate:
//         cols [3072,3088) -> gate[m][h] = sigmoid(acc + bg[h]) fp32.
// ---------------------------------------------------------------------------
#define GT 128
#define GBK 32

__global__ __launch_bounds__(256) void gemm_bf16(const ushort_t* __restrict__ A,
                                                 const ushort_t* __restrict__ B,
                                                 float* __restrict__ Cf,
                                                 ushort_t* __restrict__ Cb,
                                                 float* __restrict__ gatep,
                                                 const float* __restrict__ bgp,
                                                 int M, int N, int K,
                                                 int mode) {
    __shared__ ushort_t As[2][GT * GBK];   // 8 KB each buffer
    __shared__ ushort_t Bs[2][GT * GBK];

    const int tid = threadIdx.x;
    const int w = tid >> 6;
    const int l = tid & 63;

    // XCD swizzle: k = XCD, i = within-XCD sequence; band of 8 row tiles,
    // column-major traversal within the band.
    const int flat = blockIdx.x;
    const int kx = flat & 7;
    const int ii = flat >> 3;
    const int bx = ii >> 3;                // col tile
    const int by = (kx << 3) | (ii & 7);   // row tile (band kx)
    const int m0 = by * GT;
    const int n0 = bx * GT;

    const int wm = (w >> 1) * 64;
    const int wn = (w & 1) * 64;

    // staging: lane l -> LDS (row l>>2, slot l&3) of a 16-row segment;
    // swizzle => lane fetches global chunk (l&3) ^ ((l>>3)&3)
    const int srow = l >> 2;
    const int schunk = ((l & 3) ^ ((l >> 3) & 3)) * 8;   // elements

    const ushort_t* aseg[2];
    const ushort_t* bseg[2];
#pragma unroll
    for (int i = 0; i < 2; ++i) {
        const int s = w * 2 + i;
        aseg[i] = A + (size_t)(m0 + s * 16 + srow) * K + schunk;
        bseg[i] = B + (size_t)(n0 + s * 16 + srow) * K + schunk;
    }

#define STAGE(buf, k0)                                                          \
    do {                                                                        \
        _Pragma("unroll")                                                       \
        for (int i_ = 0; i_ < 2; ++i_) {                                        \
            const int s_ = w * 2 + i_;                                          \
            __builtin_amdgcn_global_load_lds(                                   \
                (const __attribute__((address_space(1))) unsigned int*)(const void*)(aseg[i_] + (k0)), \
                (__attribute__((address_space(3))) unsigned int*)(void*)&As[buf][s_ * 16 * GBK], \
                16, 0, 0);                                                      \
            __builtin_amdgcn_global_load_lds(                                   \
                (const __attribute__((address_space(1))) unsigned int*)(const void*)(bseg[i_] + (k0)), \
                (__attribute__((address_space(3))) unsigned int*)(void*)&Bs[buf][s_ * 16 * GBK], \
                16, 0, 0);                                                      \
        }                                                                       \
    } while (0)

    f32x4 acc[4][4];
#pragma unroll
    for (int i = 0; i < 4; ++i)
#pragma unroll
        for (int j = 0; j < 4; ++j)
#pragma unroll
            for (int r = 0; r < 4; ++r) acc[i][j][r] = 0.f;

    const int fr = l & 15;
    // swizzled fragment slot: logical chunk c = l>>4 at row ...+fr
    const int fsw = (((l >> 4) ^ ((fr >> 1) & 3))) * 8;   // elements

    STAGE(0, 0);

    const int nit = K / GBK;
    for (int it = 0; it < nit; ++it) {
        __syncthreads();                  // buf[it&1] DMA landed; old reads done
        if (it + 1 < nit) STAGE((it + 1) & 1, (it + 1) * GBK);

        const ushort_t* __restrict__ as = As[it & 1];
        const ushort_t* __restrict__ bs = Bs[it & 1];

        bf16x8 af[4], bfr[4];
#pragma unroll
        for (int ti = 0; ti < 4; ++ti)
            af[ti] = *(const bf16x8*)&as[(wm + ti * 16 + fr) * GBK + fsw];
#pragma unroll
        for (int tj = 0; tj < 4; ++tj)
            bfr[tj] = *(const bf16x8*)&bs[(wn + tj * 16 + fr) * GBK + fsw];
#pragma unroll
        for (int ti = 0; ti < 4; ++ti)
#pragma unroll
            for (int tj = 0; tj < 4; ++tj)
                acc[ti][tj] = __builtin_amdgcn_mfma_f32_16x16x32_bf16(
                    af[ti], bfr[tj], acc[ti][tj], 0, 0, 0);
    }
#undef STAGE

    const int er = (l >> 4) * 4;
    const int ec = l & 15;

    if (mode == 3 && n0 == 3072) {
        // gate tile: only cols 3072..3087 valid (wn==0, tj==0, h=ec)
#pragma unroll
        for (int ti = 0; ti < 4; ++ti)
#pragma unroll
            for (int r = 0; r < 4; ++r) {
                if (wn == 0) {
                    const int row = m0 + wm + ti * 16 + er + r;
                    const float vv = acc[ti][0][r] + bgp[ec];
                    gatep[(size_t)row * NHEADS + ec] = 1.f / (1.f + __expf(-vv));
                }
            }
        return;
    }

    // block-uniform epilogue flags
    float escale = 1.0f;
    bool do_phi = false;
    if (mode == 3) {
        do_phi = (n0 < 2048);
        escale = (n0 < 1024) ? SCALE_Q : 1.0f;
    }

#pragma unroll
    for (int ti = 0; ti < 4; ++ti)
#pragma unroll
        for (int tj = 0; tj < 4; ++tj)
#pragma unroll
            for (int r = 0; r < 4; ++r) {
                const int row = m0 + wm + ti * 16 + er + r;
                const int col = n0 + wn + tj * 16 + ec;
                float val = acc[ti][tj][r];
                if (mode == 0) {
                    Cf[(size_t)row * N + col] = val;
                } else {
                    val *= escale;
                    if (do_phi) val = (val > 0.f) ? (val + 1.f) : __expf(val);  // elu+1
                    Cb[(size_t)row * QKVS + col] = f2bf(val);
                }
            }
}

// ---------------------------------------------------------------------------
// Phase 1: per (chain, chunk) tile, decay-weighted KV outer-product sum
//   Dt[j][i] = sum_tau e^{b63 - b_tau} * v[tau][j] * k[tau][i]   (fp32)
// K',V staged FEATURE-MAJOR (transposed, decay fused into K-scatter).
// ---------------------------------------------------------------------------
__global__ __launch_bounds__(256) void p1_kernel(const ushort_t* __restrict__ qkv,
                                                 const float* __restrict__ gate,
                                                 float* __restrict__ Dt,
                                                 float* __restrict__ Bg) {
    const int tile = blockIdx.x;          // 0..2047
    const int chain = tile >> 5;
    const int c = tile & 31;
    const int b = chain >> 4;
    const int h = chain & 15;
    const int tid = threadIdx.x;
    const int w = tid >> 6;
    const int l = tid & 63;

    __shared__ ushort_t Kt[DHEAD * SP];   // Kt[i][tau], decayed
    __shared__ ushort_t Vt[DHEAD * SP];   // Vt[j][tau]
    __shared__ float bs[CT];

    const int tau = tid >> 2;
    const int seg = (tid & 3) * 16;
    const size_t grow = ((size_t)(b * SEQ + c * CT + tau)) * QKVS + h * DHEAD + seg;
    union { float4 f4[2]; ushort_t us[16]; } uk, uv;
    uk.f4[0] = *(const float4*)&qkv[grow + 1024];
    uk.f4[1] = *(const float4*)&qkv[grow + 1024 + 8];
    uv.f4[0] = *(const float4*)&qkv[grow + 2048];
    uv.f4[1] = *(const float4*)&qkv[grow + 2048 + 8];

    if (tid < 64) {
        float g = gate[((size_t)(b * SEQ + c * CT + tid)) * NHEADS + h];
        float lg = __logf(g);
#pragma unroll
        for (int d = 1; d < 64; d <<= 1) {
            float n = __shfl_up(lg, d, 64);
            if (l >= d) lg += n;
        }
        bs[tid] = lg;
        if (tid == 63) Bg[tile] = lg;
    }
    __syncthreads();

    const float e = __expf(bs[63] - bs[tau]);
#pragma unroll
    for (int f = 0; f < 16; ++f) {
        Kt[(seg + f) * SP + tau] = f2bf(e * bf2f(uk.us[f]));
        Vt[(seg + f) * SP + tau] = uv.us[f];
    }
    __syncthreads();

    const int fr = l & 15;
    const int fq = (l >> 4) * 8;
    const int jw = w * 16;

    f32x4 accD[4];
#pragma unroll
    for (int nt = 0; nt < 4; ++nt)
#pragma unroll
        for (int r = 0; r < 4; ++r) accD[nt][r] = 0.f;

#pragma unroll
    for (int kc = 0; kc < 2; ++kc) {
        bf16x8 va = *(const bf16x8*)&Vt[(jw + fr) * SP + kc * 32 + fq];
#pragma unroll
        for (int nt = 0; nt < 4; ++nt) {
            bf16x8 kf = *(const bf16x8*)&Kt[(nt * 16 + fr) * SP + kc * 32 + fq];
            accD[nt] = __builtin_amdgcn_mfma_f32_16x16x32_bf16(va, kf, accD[nt], 0, 0, 0);
        }
    }

    const int er = (l >> 4) * 4;
    const size_t dbase = (size_t)tile * (DHEAD * DHEAD);
#pragma unroll
    for (int nt = 0; nt < 4; ++nt)
#pragma unroll
        for (int r = 0; r < 4; ++r) {
            const int j = jw + er + r;
            const int i = nt * 16 + fr;
            Dt[dbase + j * DHEAD + i] = accD[nt][r];
        }
}

// ---------------------------------------------------------------------------
// Phase 2: sequential over 32 chunks; St[c] = state BEFORE chunk c (bf16,[j][i])
// ---------------------------------------------------------------------------
__global__ __launch_bounds__(256) void p2_kernel(const float* __restrict__ Dt,
                                                 const float* __restrict__ Bg,
                                                 ushort_t* __restrict__ St) {
    const int chain = blockIdx.x >> 2;
    const int jq = (blockIdx.x & 3) * 16;
    const int tid = threadIdx.x;
    const int jj = jq + (tid >> 4);
    const int ii = (tid & 15) * 4;

    float4 S = make_float4(0.f, 0.f, 0.f, 0.f);
    for (int c = 0; c < NC; ++c) {
        const size_t base = (((size_t)chain * NC + c) * DHEAD + jj) * DHEAD + ii;
        ushort4 o;
        o.x = f2bf(S.x); o.y = f2bf(S.y); o.z = f2bf(S.z); o.w = f2bf(S.w);
        *(ushort4*)&St[base] = o;
        const float eB = __expf(Bg[chain * NC + c]);
        const float4 D = *(const float4*)&Dt[base];
        S.x = eB * S.x + D.x;
        S.y = eB * S.y + D.y;
        S.z = eB * S.z + D.z;
        S.w = eB * S.w + D.w;
    }
}

// ---------------------------------------------------------------------------
// Phase 3: Y = diag(e^{b_t}) (Q@St) + (QK^T ⊙ decay ⊙ mask) @ V   -> yb bf16
// V staged feature-major; P~ LDS round-trip wave-private (no barrier).
// ---------------------------------------------------------------------------
__global__ __launch_bounds__(256) void p3_kernel(const ushort_t* __restrict__ qkv,
                                                 const ushort_t* __restrict__ St,
                                                 const float* __restrict__ gate,
                                                 ushort_t* __restrict__ yb) {
    const int tile = blockIdx.x;
    const int chain = tile >> 5;
    const int c = tile & 31;
    const int b = chain >> 4;
    const int h = chain & 15;
    const int tid = threadIdx.x;
    const int w = tid >> 6;
    const int l = tid & 63;

    __shared__ ushort_t Qs[CT * SP];
    __shared__ ushort_t Ks[CT * SP];
    __shared__ ushort_t Vt[DHEAD * SP];   // feature-major
    __shared__ ushort_t Ss[CT * SP];
    __shared__ ushort_t Ps[CT * SP];
    __shared__ float bs[CT];

    {
        const int row = tid >> 2;              // timestep tau
        const int seg = (tid & 3) * 16;
        const size_t grow = ((size_t)(b * SEQ + c * CT + row)) * QKVS + h * DHEAD + seg;
        float4 q0 = *(const float4*)&qkv[grow];
        float4 q1 = *(const float4*)&qkv[grow + 8];
        float4 k0 = *(const float4*)&qkv[grow + 1024];
        float4 k1 = *(const float4*)&qkv[grow + 1024 + 8];
        union { float4 f4[2]; ushort_t us[16]; } uv;
        uv.f4[0] = *(const float4*)&qkv[grow + 2048];
        uv.f4[1] = *(const float4*)&qkv[grow + 2048 + 8];
        const size_t srow = (((size_t)chain * NC + c) * DHEAD + row) * DHEAD + seg;
        float4 s0 = *(const float4*)&St[srow];
        float4 s1 = *(const float4*)&St[srow + 8];
        *(float4*)&Qs[row * SP + seg]     = q0;
        *(float4*)&Qs[row * SP + seg + 8] = q1;
        *(float4*)&Ks[row * SP + seg]     = k0;
        *(float4*)&Ks[row * SP + seg + 8] = k1;
        *(float4*)&Ss[row * SP + seg]     = s0;
        *(float4*)&Ss[row * SP + seg + 8] = s1;
#pragma unroll
        for (int f = 0; f < 16; ++f)
            Vt[(seg + f) * SP + row] = uv.us[f];
    }
    if (tid < 64) {
        float g = gate[((size_t)(b * SEQ + c * CT + tid)) * NHEADS + h];
        float lg = __logf(g);
#pragma unroll
        for (int d = 1; d < 64; d <<= 1) {
            float n = __shfl_up(lg, d, 64);
            if (l >= d) lg += n;
        }
        bs[tid] = lg;
    }
    __syncthreads();

    const int fr = l & 15;
    const int fq = (l >> 4) * 8;
    const int tw = w * 16;

    bf16x8 qa[2];
#pragma unroll
    for (int kc = 0; kc < 2; ++kc)
        qa[kc] = *(const bf16x8*)&Qs[(tw + fr) * SP + kc * 32 + fq];

    f32x4 accA[4], accP[4];
#pragma unroll
    for (int nt = 0; nt < 4; ++nt)
#pragma unroll
        for (int r = 0; r < 4; ++r) { accA[nt][r] = 0.f; accP[nt][r] = 0.f; }

#pragma unroll
    for (int kc = 0; kc < 2; ++kc)
#pragma unroll
        for (int nt = 0; nt < 4; ++nt) {
            bf16x8 sb = *(const bf16x8*)&Ss[(nt * 16 + fr) * SP + kc * 32 + fq];
            accA[nt] = __builtin_amdgcn_mfma_f32_16x16x32_bf16(qa[kc], sb, accA[nt], 0, 0, 0);
            bf16x8 kf = *(const bf16x8*)&Ks[(nt * 16 + fr) * SP + kc * 32 + fq];
            accP[nt] = __builtin_amdgcn_mfma_f32_16x16x32_bf16(qa[kc], kf, accP[nt], 0, 0, 0);
        }

    const int er = (l >> 4) * 4;
    int trow[4];
    float bt[4];
#pragma unroll
    for (int r = 0; r < 4; ++r) { trow[r] = tw + er + r; bt[r] = bs[trow[r]]; }
#pragma unroll
    for (int nt = 0; nt < 4; ++nt) {
        const int tau = nt * 16 + fr;
        const float btau = bs[tau];
#pragma unroll
        for (int r = 0; r < 4; ++r) {
            float f = (tau <= trow[r]) ? __expf(bt[r] - btau) : 0.f;
            Ps[trow[r] * SP + tau] = f2bf(accP[nt][r] * f);
        }
    }
    // no barrier: P~ rows are wave-private (write band == read band per wave)

    f32x4 accY[4];
#pragma unroll
    for (int r = 0; r < 4; ++r) {
        const float eb = __expf(bt[r]);
#pragma unroll
        for (int nt = 0; nt < 4; ++nt) accY[nt][r] = accA[nt][r] * eb;
    }
#pragma unroll
    for (int kc = 0; kc < 2; ++kc) {
        bf16x8 pa = *(const bf16x8*)&Ps[(tw + fr) * SP + kc * 32 + fq];
#pragma unroll
        for (int nt = 0; nt < 4; ++nt) {
            bf16x8 vf = *(const bf16x8*)&Vt[(nt * 16 + fr) * SP + kc * 32 + fq];
            accY[nt] = __builtin_amdgcn_mfma_f32_16x16x32_bf16(pa, vf, accY[nt], 0, 0, 0);
        }
    }

    const size_t ybase = ((size_t)(b * SEQ + c * CT)) * DMODEL + h * DHEAD;
#pragma unroll
    for (int nt = 0; nt < 4; ++nt)
#pragma unroll
        for (int r = 0; r < 4; ++r)
            yb[ybase + (size_t)trow[r] * DMODEL + nt * 16 + fr] = f2bf(accY[nt][r]);
}

// ---------------------------------------------------------------------------
// Host launch
// ---------------------------------------------------------------------------
extern "C" void kernel_launch(void* const* d_in, const int* in_sizes, int n_in,
                              void* d_out, int out_size, void* d_ws, size_t ws_size,
                              hipStream_t stream) {
    const float* x  = (const float*)d_in[0];
    const float* Wq = (const float*)d_in[1];
    const float* Wk = (const float*)d_in[2];
    const float* Wv = (const float*)d_in[3];
    const float* Wo = (const float*)d_in[4];
    const float* Wg = (const float*)d_in[5];
    const float* bg = (const float*)d_in[6];
    float* out = (float*)d_out;

    const size_t elems = (size_t)MTOK * DMODEL;     // 8,388,608
    const size_t welems = (size_t)DMODEL * DMODEL;  // 1,048,576
    const size_t stelems = (size_t)NCHAIN * NC * DHEAD * DHEAD;   // 8,388,608

    // layout with aliasing:
    // [xb | St (after p2)] [qkv] [wcat 4224 rows] [gate f32] [Bg f32] [Dt f32 | yb]
    ushort_t* xb   = (ushort_t*)d_ws;
    ushort_t* St   = xb;                            // alias: xb dead after QKV gemm
    ushort_t* qkv  = xb + elems;                    // [8192][3072]
    ushort_t* wcat = qkv + (size_t)MTOK * QKVS;
    float* gate    = (float*)(wcat + (size_t)WROWS * DMODEL);
    float* Bg      = gate + (size_t)MTOK * NHEADS;
    float* Dt      = Bg + (size_t)NCHAIN * NC;
    ushort_t* yb   = (ushort_t*)Dt;                 // alias: Dt dead after p2

    const size_t need = (size_t)((char*)(Dt + stelems) - (char*)d_ws);  // ~106 MB
    if (ws_size < need) return;

    // converts (pure bandwidth)
    cvt_all<<<dim3(MTOK + WROWS), dim3(256), 0, stream>>>(x, Wq, Wk, Wv, Wo, Wg, xb, wcat);

    // fused QKV + gate projection: 25 col tiles (24 qkv + 1 gate), XCD-swizzled
    gemm_bf16<<<dim3(25 * 64), dim3(256), 0, stream>>>(
        xb, wcat, nullptr, qkv, gate, bg, MTOK, QKVS, DMODEL, 3);

    // chunked linear-attention scan
    p1_kernel<<<dim3(NCHAIN * NC), dim3(256), 0, stream>>>(qkv, gate, Dt, Bg);
    p2_kernel<<<dim3(NCHAIN * 4), dim3(256), 0, stream>>>(Dt, Bg, St);
    p3_kernel<<<dim3(NCHAIN * NC), dim3(256), 0, stream>>>(qkv, St, gate, yb);

    // output projection (fp32 out), Wo at wcat rows [3200,4224), XCD-swizzled
    gemm_bf16<<<dim3(8 * 64), dim3(256), 0, stream>>>(
        yb, wcat + (size_t)3200 * DMODEL, out, nullptr, nullptr, nullptr,
        MTOK, DMODEL, DMODEL, 0);
}